// Round 1
// baseline (646.008 us; speedup 1.0000x reference)
//
#include <hip/hip_runtime.h>
#include <hip/hip_bf16.h>
#include <stdint.h>

// ---------------------------------------------------------------------------
// TransformerSeqLayer: rel-pos sliding-window attention + post-LN + top-2 MoE
// All heavy matmuls on MFMA f16 16x16x32.
// Pre-gate path uses f16x2 split (hi + lo*2^-11, lo stored pre-scaled by 2^11)
// with dual accumulators => ~2^-22 relative error so top_idx matches fp32 ref.
// MoE path uses single f16 (0.14 absmax threshold is generous).
// ---------------------------------------------------------------------------

typedef _Float16 f16;
typedef _Float16 f16x8 __attribute__((ext_vector_type(8)));
typedef _Float16 f16x4 __attribute__((ext_vector_type(4)));
typedef float    f32x4 __attribute__((ext_vector_type(4)));
typedef int      i32x4 __attribute__((ext_vector_type(4)));

#define MFMA16(a, b, c) __builtin_amdgcn_mfma_f32_16x16x32_f16((a), (b), (c), 0, 0, 0)
#define LO_SCALE 2048.0f
#define LO_INV   4.8828125e-4f   // 1/2048

__device__ __forceinline__ void split2(float x, f16* h, f16* l) {
  f16 hh = (f16)x;
  *h = hh;
  *l = (f16)((x - (float)hh) * LO_SCALE);
}

__device__ __forceinline__ f32x4 zero4() {
  f32x4 z; z[0] = 0.f; z[1] = 0.f; z[2] = 0.f; z[3] = 0.f; return z;
}

// ---------------------------------------------------------------------------
// Cast h_all = concat(h_cache, h) -> split planes [B*1024][1024]
// ---------------------------------------------------------------------------
__global__ void __launch_bounds__(256) cast_hall_k(const float* __restrict__ h,
                                                   const float* __restrict__ hc,
                                                   f16* __restrict__ hi,
                                                   f16* __restrict__ lo) {
  int c = blockIdx.x * 256 + threadIdx.x;   // chunk of 8 elems
  int e0 = c * 8;
  int row = e0 >> 10;
  int col = e0 & 1023;
  int b = row >> 10, pos = row & 1023;
  const float* src = (pos < 512) ? (hc + (size_t)((b << 9) + pos) * 1024 + col)
                                 : (h  + (size_t)((b << 9) + (pos - 512)) * 1024 + col);
  float4 v0 = ((const float4*)src)[0];
  float4 v1 = ((const float4*)src)[1];
  float xs[8] = {v0.x, v0.y, v0.z, v0.w, v1.x, v1.y, v1.z, v1.w};
  f16x8 vh, vl;
#pragma unroll
  for (int i = 0; i < 8; i++) { f16 a, bb; split2(xs[i], &a, &bb); vh[i] = a; vl[i] = bb; }
  *(f16x8*)&hi[e0] = vh;
  *(f16x8*)&lo[e0] = vl;
}

// ---------------------------------------------------------------------------
// Transpose + cast: in [R][C] fp32 -> out [C][R] f16 (split optional)
// ---------------------------------------------------------------------------
template <int SPLIT>
__global__ void __launch_bounds__(256) transpose_cast_k(const float* __restrict__ in,
                                                        f16* __restrict__ oh,
                                                        f16* __restrict__ ol,
                                                        int R, int C) {
  in += (size_t)blockIdx.z * R * C;
  oh += (size_t)blockIdx.z * R * C;
  if constexpr (SPLIT) ol += (size_t)blockIdx.z * R * C;
  __shared__ float tile[32][33];
  int c0 = blockIdx.x * 32, r0 = blockIdx.y * 32;
  int tr = threadIdx.x >> 3, tc = (threadIdx.x & 7) * 4;
  float4 v = *(const float4*)&in[(size_t)(r0 + tr) * C + c0 + tc];
  tile[tr][tc + 0] = v.x; tile[tr][tc + 1] = v.y; tile[tr][tc + 2] = v.z; tile[tr][tc + 3] = v.w;
  __syncthreads();
  int oc = tr;       // output row index within tile (input col)
  int orr = tc;      // output col group (input row)
  f16x4 vh, vl;
#pragma unroll
  for (int i = 0; i < 4; i++) {
    float x = tile[orr + i][oc];
    f16 a, bb; split2(x, &a, &bb);
    vh[i] = a; vl[i] = bb;
  }
  *(f16x4*)&oh[(size_t)(c0 + oc) * R + r0 + orr] = vh;
  if constexpr (SPLIT) *(f16x4*)&ol[(size_t)(c0 + oc) * R + r0 + orr] = vl;
}

// ---------------------------------------------------------------------------
// Generic NT GEMM: C[row][col] = sum_k A[row][k] * B[col][k]
// A: [rows][K] (hi/lo planes), B: [N][K] (transposed weights, hi/lo planes)
// SPLIT=1: dual accumulator f16x2 correction. Tile: 128 x (SPLIT?64:128), BK=32.
// ---------------------------------------------------------------------------
#define AM_ID 0
#define AM_Q  1
#define AM_GA 2
#define AM_PA 3
#define EP_QK 0
#define EP_VT 1
#define EP_F32 2
#define EP_HE 3
#define EP_YE 4

template <int SPLIT, int AMAP, int EPI>
__global__ void __launch_bounds__(256) gemm_k(
    const f16* __restrict__ Ah, const f16* __restrict__ Al,
    const f16* __restrict__ Bh, const f16* __restrict__ Bl,
    void* __restrict__ o0, void* __restrict__ o1,
    const float* __restrict__ bias,
    int Kd, int strideA, int lgRPB, int bExpStride,
    const int* __restrict__ list, const int* __restrict__ bases,
    const int* __restrict__ counts) {
  constexpr int PL = SPLIT ? 2 : 1;
  constexpr int BN = SPLIT ? 64 : 128;
  constexpr int NT = BN / 32;            // n-tiles per wave
  const int e = blockIdx.z;
  int cnt = 0, base0 = 0;
  if constexpr (AMAP == AM_GA || AMAP == AM_PA) {
    cnt = counts[e]; base0 = bases[e];
    if ((int)blockIdx.y * 128 >= cnt) return;
    Bh += (size_t)e * bExpStride;
  }
  __shared__ f16 sA[PL][128 * 32];
  __shared__ f16 sB[PL][BN * 32];
  const int n0 = blockIdx.x * BN, r0 = blockIdx.y * 128;
  const int tid = threadIdx.x, lane = tid & 63, wv = tid >> 6;
  const int wm = (wv >> 1) * 64, wn = (wv & 1) * (BN / 2);

  f32x4 accM[4][NT], accC[4][NT];
#pragma unroll
  for (int i = 0; i < 4; i++)
#pragma unroll
    for (int j = 0; j < NT; j++) { accM[i][j] = zero4(); accC[i][j] = zero4(); }

  // precompute A staging rows (constant over K loop)
  int aRow[2], aCu[2];
#pragma unroll
  for (int c = 0; c < 2; c++) {
    int u = c * 256 + tid;
    int r = u >> 2, cu = u & 3;
    aCu[c] = ((cu ^ ((r >> 1) & 3)) << 3);
    int rr = r0 + r;
    int g;
    if constexpr (AMAP == AM_ID) g = rr;
    else if constexpr (AMAP == AM_Q) g = ((rr >> 9) << 10) + 512 + (rr & 511);
    else if constexpr (AMAP == AM_GA) g = (rr < cnt) ? list[base0 + rr] : 0;
    else g = base0 + rr;
    aRow[c] = g;
  }

  for (int k0 = 0; k0 < Kd; k0 += 32) {
    // stage A (512 16B units) and B (BN*4 units), XOR-swizzled on 16B units
#pragma unroll
    for (int c = 0; c < 2; c++) {
      int u = c * 256 + tid;
      int scol = k0 + aCu[c];
      *(f16x8*)&sA[0][u * 8] = *(const f16x8*)&Ah[(size_t)aRow[c] * strideA + scol];
      if constexpr (SPLIT)
        *(f16x8*)&sA[1][u * 8] = *(const f16x8*)&Al[(size_t)aRow[c] * strideA + scol];
    }
#pragma unroll
    for (int c = 0; c * 256 < BN * 4; c++) {
      int u = c * 256 + tid;
      int r = u >> 2, cu = u & 3;
      int scol = k0 + ((cu ^ ((r >> 1) & 3)) << 3);
      int gb = n0 + r;
      *(f16x8*)&sB[0][u * 8] = *(const f16x8*)&Bh[(size_t)gb * Kd + scol];
      if constexpr (SPLIT)
        *(f16x8*)&sB[1][u * 8] = *(const f16x8*)&Bl[(size_t)gb * Kd + scol];
    }
    __syncthreads();

    f16x8 ah[4], al[4];
#pragma unroll
    for (int mt = 0; mt < 4; mt++) {
      int r = wm + mt * 16 + (lane & 15);
      int cu = (lane >> 4) ^ ((r >> 1) & 3);
      ah[mt] = *(const f16x8*)&sA[0][(r * 4 + cu) * 8];
      if constexpr (SPLIT) al[mt] = *(const f16x8*)&sA[1][(r * 4 + cu) * 8];
    }
#pragma unroll
    for (int nt = 0; nt < NT; nt++) {
      int r = wn + nt * 16 + (lane & 15);
      int cu = (lane >> 4) ^ ((r >> 1) & 3);
      f16x8 bh = *(const f16x8*)&sB[0][(r * 4 + cu) * 8];
      f16x8 bl;
      if constexpr (SPLIT) bl = *(const f16x8*)&sB[1][(r * 4 + cu) * 8];
#pragma unroll
      for (int mt = 0; mt < 4; mt++) {
        accM[mt][nt] = MFMA16(ah[mt], bh, accM[mt][nt]);
        if constexpr (SPLIT) {
          accC[mt][nt] = MFMA16(ah[mt], bl, accC[mt][nt]);
          accC[mt][nt] = MFMA16(al[mt], bh, accC[mt][nt]);
        }
      }
    }
    __syncthreads();
  }

  // epilogue
#pragma unroll
  for (int mt = 0; mt < 4; mt++)
#pragma unroll
    for (int nt = 0; nt < NT; nt++)
#pragma unroll
      for (int rg = 0; rg < 4; rg++) {
        int row = r0 + wm + mt * 16 + ((lane >> 4) << 2) + rg;
        int col = n0 + wn + nt * 16 + (lane & 15);
        float v = accM[mt][nt][rg];
        if constexpr (SPLIT) v += accC[mt][nt][rg] * LO_INV;
        if constexpr (EPI == EP_QK) {
          int bq = row >> lgRPB, pos = row & ((1 << lgRPB) - 1);
          size_t ad = ((size_t)((((bq << 3) + (col >> 7)) << lgRPB) + pos)) * 128 + (col & 127);
          f16 hh, ll; split2(v, &hh, &ll);
          ((f16*)o0)[ad] = hh; ((f16*)o1)[ad] = ll;
        } else if constexpr (EPI == EP_VT) {
          size_t ad = ((size_t)(((row >> 10) << 3) + (col >> 7)) * 128 + (col & 127)) * 1024 + (row & 1023);
          f16 hh, ll; split2(v, &hh, &ll);
          ((f16*)o0)[ad] = hh; ((f16*)o1)[ad] = ll;
        } else if constexpr (EPI == EP_F32) {
          ((float*)o0)[(size_t)row * 1024 + col] = v;
        } else if constexpr (EPI == EP_HE) {
          if (row < cnt) {
            float t = v + bias[(e << 11) + col];
            ((f16*)o0)[(size_t)(base0 + row) * 2048 + col] = (f16)fmaxf(t, 0.f);
          }
        } else if constexpr (EPI == EP_YE) {
          if (row < cnt)
            ((float*)o0)[(size_t)(base0 + row) * 1024 + col] = v + bias[(e << 10) + col];
        }
      }
}

// ---------------------------------------------------------------------------
// Windowed relative-position attention.
// One block = (b*8+head, 32 query rows). Window = 544 keys (32+512).
// S[32][548] in LDS: fp32 scores -> packed split-f16 probabilities in place.
// ---------------------------------------------------------------------------
__device__ __forceinline__ void unpack_p(const unsigned* sp, f16x8* hi, f16x8* lo) {
  i32x4 u0 = *(const i32x4*)sp;
  i32x4 u1 = *(const i32x4*)(sp + 4);
  i32x4 h, l;
  h[0] = (u0[0] & 0xffff) | (u0[1] << 16);
  h[1] = (u0[2] & 0xffff) | (u0[3] << 16);
  h[2] = (u1[0] & 0xffff) | (u1[1] << 16);
  h[3] = (u1[2] & 0xffff) | (u1[3] << 16);
  l[0] = (int)(((unsigned)u0[0] >> 16) | ((unsigned)u0[1] & 0xffff0000u));
  l[1] = (int)(((unsigned)u0[2] >> 16) | ((unsigned)u0[3] & 0xffff0000u));
  l[2] = (int)(((unsigned)u1[0] >> 16) | ((unsigned)u1[1] & 0xffff0000u));
  l[3] = (int)(((unsigned)u1[2] >> 16) | ((unsigned)u1[3] & 0xffff0000u));
  *hi = __builtin_bit_cast(f16x8, h);
  *lo = __builtin_bit_cast(f16x8, l);
}

__global__ void __launch_bounds__(256) attn_k(
    const f16* __restrict__ qh_, const f16* __restrict__ ql_,
    const f16* __restrict__ kh_, const f16* __restrict__ kl_,
    const f16* __restrict__ ph_, const f16* __restrict__ pl_,
    const f16* __restrict__ vh_, const f16* __restrict__ vl_,
    f16* __restrict__ oh_, f16* __restrict__ ol_) {
  __shared__ float S[32][548];
  const int bh = blockIdx.y;
  const int m0 = blockIdx.x * 32;
  const int tid = threadIdx.x, lane = tid & 63, wv = tid >> 6;
  const int lr = lane & 15, lgp = lane >> 4;

  // Q fragments (held in registers)
  f16x8 qh[2][4], ql[2][4];
  {
    const size_t qbase = ((size_t)bh * 512 + m0) * 128;
#pragma unroll
    for (int mt = 0; mt < 2; mt++)
#pragma unroll
      for (int kb = 0; kb < 4; kb++) {
        size_t off = qbase + (size_t)(mt * 16 + lr) * 128 + kb * 32 + lgp * 8;
        qh[mt][kb] = *(const f16x8*)&qh_[off];
        ql[mt][kb] = *(const f16x8*)&ql_[off];
      }
  }

  // phase 1: content scores  S[m][j] = q[m] . k[m0+j]
  {
    const size_t kbase = ((size_t)bh * 1024 + m0) * 128;
    int ntB = (wv < 2) ? wv * 9 : 18 + (wv - 2) * 8;
    int ntE = ntB + ((wv < 2) ? 9 : 8);
    for (int nt = ntB; nt < ntE; ++nt) {
      f16x8 kh[4], kl[4];
#pragma unroll
      for (int kb = 0; kb < 4; kb++) {
        size_t off = kbase + (size_t)(nt * 16 + lr) * 128 + kb * 32 + lgp * 8;
        kh[kb] = *(const f16x8*)&kh_[off];
        kl[kb] = *(const f16x8*)&kl_[off];
      }
      f32x4 aM[2], aC[2];
      aM[0] = zero4(); aM[1] = zero4(); aC[0] = zero4(); aC[1] = zero4();
#pragma unroll
      for (int kb = 0; kb < 4; kb++)
#pragma unroll
        for (int mt = 0; mt < 2; mt++) {
          aM[mt] = MFMA16(qh[mt][kb], kh[kb], aM[mt]);
          aC[mt] = MFMA16(qh[mt][kb], kl[kb], aC[mt]);
          aC[mt] = MFMA16(ql[mt][kb], kh[kb], aC[mt]);
        }
#pragma unroll
      for (int mt = 0; mt < 2; mt++)
#pragma unroll
        for (int rg = 0; rg < 4; rg++) {
          int m = mt * 16 + lgp * 4 + rg;
          S[m][nt * 16 + lr] = aM[mt][rg] + aC[mt][rg] * LO_INV;
        }
    }
  }
  __syncthreads();

  // phase 2: positional scores  S[m][m+l] += q[m] . pe[l]
  {
    for (int lt = wv * 8; lt < wv * 8 + 8; ++lt) {
      f16x8 eh[4], el[4];
#pragma unroll
      for (int kb = 0; kb < 4; kb++) {
        size_t off = (size_t)(lt * 16 + lr) * 128 + kb * 32 + lgp * 8;
        eh[kb] = *(const f16x8*)&ph_[off];
        el[kb] = *(const f16x8*)&pl_[off];
      }
      f32x4 aM[2], aC[2];
      aM[0] = zero4(); aM[1] = zero4(); aC[0] = zero4(); aC[1] = zero4();
#pragma unroll
      for (int kb = 0; kb < 4; kb++)
#pragma unroll
        for (int mt = 0; mt < 2; mt++) {
          aM[mt] = MFMA16(qh[mt][kb], eh[kb], aM[mt]);
          aC[mt] = MFMA16(qh[mt][kb], el[kb], aC[mt]);
          aC[mt] = MFMA16(ql[mt][kb], eh[kb], aC[mt]);
        }
#pragma unroll
      for (int mt = 0; mt < 2; mt++)
#pragma unroll
        for (int rg = 0; rg < 4; rg++) {
          int m = mt * 16 + lgp * 4 + rg;
          int lc = lt * 16 + lr;
          S[m][m + lc] += aM[mt][rg] + aC[mt][rg] * LO_INV;
        }
    }
  }
  __syncthreads();

  // phase 3: softmax over each row's valid window [m, m+512), write packed split P
  {
    const float scl = 0.08838834764831843f;  // 1/sqrt(128)
    for (int rr = 0; rr < 8; ++rr) {
      int m = wv * 8 + rr;
      float mx = -3.0e38f;
#pragma unroll
      for (int it = 0; it < 9; ++it) {
        int j = it * 64 + lane;
        if (j < 544 && j >= m && j < m + 512) mx = fmaxf(mx, S[m][j]);
      }
#pragma unroll
      for (int o = 32; o > 0; o >>= 1) mx = fmaxf(mx, __shfl_xor(mx, o));
      float pv[9]; float sm = 0.f;
#pragma unroll
      for (int it = 0; it < 9; ++it) {
        int j = it * 64 + lane;
        float p = 0.f;
        if (j < 544 && j >= m && j < m + 512) p = expf((S[m][j] - mx) * scl);
        pv[it] = p; sm += p;
      }
#pragma unroll
      for (int o = 32; o > 0; o >>= 1) sm += __shfl_xor(sm, o);
      float inv = 1.0f / sm;
#pragma unroll
      for (int it = 0; it < 9; ++it) {
        int j = it * 64 + lane;
        if (j < 544) {
          float pn = pv[it] * inv;
          f16 hh, ll; split2(pn, &hh, &ll);
          unsigned pk = (unsigned)__builtin_bit_cast(unsigned short, hh) |
                        ((unsigned)__builtin_bit_cast(unsigned short, ll) << 16);
          ((unsigned*)&S[m][0])[j] = pk;
        }
      }
    }
  }
  __syncthreads();

  // phase 4: O[m][d] = sum_j P[m][j] * V[m0+j][d]   (V stored transposed [d][pos])
  f32x4 accM[2][2], accC[2][2];
#pragma unroll
  for (int i = 0; i < 2; i++)
#pragma unroll
    for (int j = 0; j < 2; j++) { accM[i][j] = zero4(); accC[i][j] = zero4(); }
  for (int kb = 0; kb < 17; ++kb) {
    f16x8 pah[2], pal[2];
#pragma unroll
    for (int mt = 0; mt < 2; mt++) {
      const unsigned* sp = (const unsigned*)&S[mt * 16 + lr][0] + kb * 32 + lgp * 8;
      unpack_p(sp, &pah[mt], &pal[mt]);
    }
#pragma unroll
    for (int ntl = 0; ntl < 2; ++ntl) {
      int d = wv * 32 + ntl * 16 + lr;
      size_t off = ((size_t)bh * 128 + d) * 1024 + m0 + kb * 32 + lgp * 8;
      f16x8 vh = *(const f16x8*)&vh_[off];
      f16x8 vl = *(const f16x8*)&vl_[off];
#pragma unroll
      for (int mt = 0; mt < 2; mt++) {
        accM[mt][ntl] = MFMA16(pah[mt], vh, accM[mt][ntl]);
        accC[mt][ntl] = MFMA16(pah[mt], vl, accC[mt][ntl]);
        accC[mt][ntl] = MFMA16(pal[mt], vh, accC[mt][ntl]);
      }
    }
  }
  const int b = bh >> 3, hd = bh & 7;
#pragma unroll
  for (int mt = 0; mt < 2; mt++)
#pragma unroll
    for (int ntl = 0; ntl < 2; ntl++)
#pragma unroll
      for (int rg = 0; rg < 4; rg++) {
        int m = mt * 16 + lgp * 4 + rg;
        int d = wv * 32 + ntl * 16 + lr;
        float v = accM[mt][ntl][rg] + accC[mt][ntl][rg] * LO_INV;
        size_t ad = ((size_t)(b * 512 + m0 + m)) * 1024 + hd * 128 + d;
        f16 hh, ll; split2(v, &hh, &ll);
        oh_[ad] = hh; ol_[ad] = ll;
      }
}

// ---------------------------------------------------------------------------
// LayerNorm helpers / kernels (fp32)
// ---------------------------------------------------------------------------
__device__ __forceinline__ float blk_sum(float v, float* red) {
#pragma unroll
  for (int o = 32; o > 0; o >>= 1) v += __shfl_xor(v, o);
  int wv = threadIdx.x >> 6;
  if ((threadIdx.x & 63) == 0) red[wv] = v;
  __syncthreads();
  float r = red[0] + red[1] + red[2] + red[3];
  __syncthreads();
  return r;
}

__global__ void __launch_bounds__(256) ln1_k(const float* __restrict__ h,
                                             const float* __restrict__ ap,
                                             const float* __restrict__ g,
                                             const float* __restrict__ bb,
                                             float* __restrict__ h1,
                                             f16* __restrict__ h1h) {
  int row = blockIdx.x;
  __shared__ float red[4];
  float4 hv = ((const float4*)(h + (size_t)row * 1024))[threadIdx.x];
  float4 av = ((const float4*)(ap + (size_t)row * 1024))[threadIdx.x];
  float4 x; x.x = hv.x + av.x; x.y = hv.y + av.y; x.z = hv.z + av.z; x.w = hv.w + av.w;
  float s = x.x + x.y + x.z + x.w;
  s = blk_sum(s, red);
  float mean = s * (1.0f / 1024.0f);
  float4 d; d.x = x.x - mean; d.y = x.y - mean; d.z = x.z - mean; d.w = x.w - mean;
  float s2 = d.x * d.x + d.y * d.y + d.z * d.z + d.w * d.w;
  s2 = blk_sum(s2, red);
  float var = s2 * (1.0f / 1024.0f);
  float inv = 1.0f / sqrtf(var + 1e-5f);
  float4 gv = ((const float4*)g)[threadIdx.x];
  float4 bv = ((const float4*)bb)[threadIdx.x];
  float4 y; y.x = d.x * inv * gv.x + bv.x; y.y = d.y * inv * gv.y + bv.y;
  y.z = d.z * inv * gv.z + bv.z; y.w = d.w * inv * gv.w + bv.w;
  ((float4*)(h1 + (size_t)row * 1024))[threadIdx.x] = y;
  f16x4 yh; yh[0] = (f16)y.x; yh[1] = (f16)y.y; yh[2] = (f16)y.z; yh[3] = (f16)y.w;
  *(f16x4*)&h1h[(size_t)row * 1024 + threadIdx.x * 4] = yh;
}

// ---------------------------------------------------------------------------
// Gate: logits = h1 @ gate_W + gate_b, top-2, softmax, counts
// ---------------------------------------------------------------------------
__global__ void __launch_bounds__(256) gate_k(const float* __restrict__ h1,
                                              const float* __restrict__ gW,
                                              const float* __restrict__ gb,
                                              float* __restrict__ outIdx,
                                              float* __restrict__ sc,
                                              int* __restrict__ te,
                                              int* __restrict__ ctrl) {
  int t = blockIdx.x * 4 + (threadIdx.x >> 6);
  int lane = threadIdx.x & 63;
  float a0 = 0, a1 = 0, a2 = 0, a3 = 0, a4 = 0, a5 = 0, a6 = 0, a7 = 0;
  for (int i = lane; i < 1024; i += 64) {
    float x = h1[(size_t)t * 1024 + i];
    const float4* w = (const float4*)&gW[i * 8];
    float4 w0 = w[0], w1 = w[1];
    a0 += x * w0.x; a1 += x * w0.y; a2 += x * w0.z; a3 += x * w0.w;
    a4 += x * w1.x; a5 += x * w1.y; a6 += x * w1.z; a7 += x * w1.w;
  }
  float av[8] = {a0, a1, a2, a3, a4, a5, a6, a7};
#pragma unroll
  for (int e = 0; e < 8; e++)
#pragma unroll
    for (int o = 32; o > 0; o >>= 1) av[e] += __shfl_xor(av[e], o);
  if (lane == 0) {
#pragma unroll
    for (int e = 0; e < 8; e++) av[e] += gb[e];
    int i0 = 0; float v0 = av[0];
#pragma unroll
    for (int e = 1; e < 8; e++) if (av[e] > v0) { v0 = av[e]; i0 = e; }
    int i1 = -1; float v1 = -3.0e38f;
#pragma unroll
    for (int e = 0; e < 8; e++) if (e != i0 && av[e] > v1) { v1 = av[e]; i1 = e; }
    float ex = expf(v1 - v0);
    float den = 1.0f + ex;
    outIdx[t * 2] = (float)i0; outIdx[t * 2 + 1] = (float)i1;
    sc[t * 2] = 1.0f / den; sc[t * 2 + 1] = ex / den;
    te[t * 2] = i0; te[t * 2 + 1] = i1;
    atomicAdd(&ctrl[i0], 1); atomicAdd(&ctrl[i1], 1);
  }
}

__global__ void scan_k(int* ctrl) {
  if (threadIdx.x == 0 && blockIdx.x == 0) {
    int s = 0;
    for (int e = 0; e < 8; e++) { ctrl[8 + e] = s; s += ctrl[e]; }
  }
}

__global__ void __launch_bounds__(256) scatter_k(const int* __restrict__ te,
                                                 int* ctrl,
                                                 int* __restrict__ list,
                                                 int* __restrict__ ppos) {
  int t = blockIdx.x * 256 + threadIdx.x;
  if (t >= 2048) return;
#pragma unroll
  for (int s = 0; s < 2; s++) {
    int e = te[t * 2 + s];
    int pos = atomicAdd(&ctrl[16 + e], 1);
    int pr = ctrl[8 + e] + pos;
    list[pr] = t;
    ppos[t * 2 + s] = pr;
  }
}

// ---------------------------------------------------------------------------
// Combine MoE outputs + final LayerNorm
// ---------------------------------------------------------------------------
__global__ void __launch_bounds__(256) comb_ln2_k(const float* __restrict__ h1,
                                                  const float* __restrict__ ye,
                                                  const float* __restrict__ sc,
                                                  const int* __restrict__ ppos,
                                                  const float* __restrict__ g,
                                                  const float* __restrict__ bb,
                                                  float* __restrict__ out) {
  int row = blockIdx.x;
  __shared__ float red[4];
  int p0 = ppos[row * 2], p1 = ppos[row * 2 + 1];
  float s0 = sc[row * 2], s1 = sc[row * 2 + 1];
  float4 a = ((const float4*)(h1 + (size_t)row * 1024))[threadIdx.x];
  float4 y0 = ((const float4*)(ye + (size_t)p0 * 1024))[threadIdx.x];
  float4 y1 = ((const float4*)(ye + (size_t)p1 * 1024))[threadIdx.x];
  float4 x;
  x.x = a.x + s0 * y0.x + s1 * y1.x; x.y = a.y + s0 * y0.y + s1 * y1.y;
  x.z = a.z + s0 * y0.z + s1 * y1.z; x.w = a.w + s0 * y0.w + s1 * y1.w;
  float s = x.x + x.y + x.z + x.w;
  s = blk_sum(s, red);
  float mean = s * (1.0f / 1024.0f);
  float4 d; d.x = x.x - mean; d.y = x.y - mean; d.z = x.z - mean; d.w = x.w - mean;
  float s2 = d.x * d.x + d.y * d.y + d.z * d.z + d.w * d.w;
  s2 = blk_sum(s2, red);
  float var = s2 * (1.0f / 1024.0f);
  float inv = 1.0f / sqrtf(var + 1e-5f);
  float4 gv = ((const float4*)g)[threadIdx.x];
  float4 bv = ((const float4*)bb)[threadIdx.x];
  float4 y; y.x = d.x * inv * gv.x + bv.x; y.y = d.y * inv * gv.y + bv.y;
  y.z = d.z * inv * gv.z + bv.z; y.w = d.w * inv * gv.w + bv.w;
  ((float4*)(out + (size_t)row * 1024))[threadIdx.x] = y;
}

// ---------------------------------------------------------------------------
// Host launch
// ---------------------------------------------------------------------------
extern "C" void kernel_launch(void* const* d_in, const int* in_sizes, int n_in,
                              void* d_out, int out_size, void* d_ws, size_t ws_size,
                              hipStream_t stream) {
  const float* h   = (const float*)d_in[0];
  const float* hc  = (const float*)d_in[1];
  const float* pe  = (const float*)d_in[2];
  const float* Wq  = (const float*)d_in[3];
  const float* Wk  = (const float*)d_in[4];
  const float* Wv  = (const float*)d_in[5];
  const float* Wo  = (const float*)d_in[6];
  const float* g1  = (const float*)d_in[7];
  const float* b1n = (const float*)d_in[8];
  const float* gW  = (const float*)d_in[9];
  const float* gb  = (const float*)d_in[10];
  const float* W1  = (const float*)d_in[11];
  const float* b1e = (const float*)d_in[12];
  const float* W2  = (const float*)d_in[13];
  const float* b2e = (const float*)d_in[14];
  const float* g2  = (const float*)d_in[15];
  const float* b2n = (const float*)d_in[16];
  float* out = (float*)d_out;
  float* outIdx = out + 2097152;

  char* w = (char*)d_ws;
  size_t off = 0;
  auto alloc = [&](size_t bytes) -> char* {
    char* p = w + off;
    off += (bytes + 255) & ~(size_t)255;
    return p;
  };
  int*   ctrl  = (int*)alloc(128);
  f16*   hallH = (f16*)alloc(4096ull * 1024 * 2);
  f16*   hallL = (f16*)alloc(4096ull * 1024 * 2);
  f16*   WqtH  = (f16*)alloc(1024ull * 1024 * 2);
  f16*   WqtL  = (f16*)alloc(1024ull * 1024 * 2);
  f16*   WktH  = (f16*)alloc(1024ull * 1024 * 2);
  f16*   WktL  = (f16*)alloc(1024ull * 1024 * 2);
  f16*   WvtH  = (f16*)alloc(1024ull * 1024 * 2);
  f16*   WvtL  = (f16*)alloc(1024ull * 1024 * 2);
  f16*   WotH  = (f16*)alloc(1024ull * 1024 * 2);
  f16*   WotL  = (f16*)alloc(1024ull * 1024 * 2);
  f16*   peH   = (f16*)alloc(512ull * 128 * 2);
  f16*   peL   = (f16*)alloc(512ull * 128 * 2);
  f16*   qH    = (f16*)alloc(2097152ull * 2);
  f16*   qL    = (f16*)alloc(2097152ull * 2);
  f16*   kH    = (f16*)alloc(4194304ull * 2);
  f16*   kL    = (f16*)alloc(4194304ull * 2);
  f16*   vtH   = (f16*)alloc(4194304ull * 2);
  f16*   vtL   = (f16*)alloc(4194304ull * 2);
  f16*   attH  = (f16*)alloc(2097152ull * 2);
  f16*   attL  = (f16*)alloc(2097152ull * 2);
  float* aproj = (float*)alloc(2097152ull * 4);
  float* h1    = (float*)alloc(2097152ull * 4);
  f16*   h1h   = (f16*)alloc(2097152ull * 2);
  f16*   W1t   = (f16*)alloc(16777216ull * 2);
  f16*   W2t   = (f16*)alloc(16777216ull * 2);
  f16*   he    = (f16*)alloc(4224ull * 2048 * 2);
  float* ye    = (float*)alloc(4224ull * 1024 * 4);
  float* scb   = (float*)alloc(2048ull * 2 * 4);
  int*   te    = (int*)alloc(2048ull * 2 * 4);
  int*   ppos  = (int*)alloc(2048ull * 2 * 4);
  int*   list  = (int*)alloc(4096ull * 4);
  (void)in_sizes; (void)n_in; (void)out_size; (void)ws_size;

  hipMemsetAsync(ctrl, 0, 128, stream);

  // casts / transposes
  cast_hall_k<<<2048, 256, 0, stream>>>(h, hc, hallH, hallL);
  transpose_cast_k<1><<<dim3(32, 32, 1), 256, 0, stream>>>(Wq, WqtH, WqtL, 1024, 1024);
  transpose_cast_k<1><<<dim3(32, 32, 1), 256, 0, stream>>>(Wk, WktH, WktL, 1024, 1024);
  transpose_cast_k<1><<<dim3(32, 32, 1), 256, 0, stream>>>(Wv, WvtH, WvtL, 1024, 1024);
  transpose_cast_k<1><<<dim3(32, 32, 1), 256, 0, stream>>>(Wo, WotH, WotL, 1024, 1024);
  transpose_cast_k<1><<<dim3(16, 4, 1), 256, 0, stream>>>(pe, peH, peL, 128, 512);
  transpose_cast_k<0><<<dim3(64, 32, 8), 256, 0, stream>>>(W1, W1t, nullptr, 1024, 2048);
  transpose_cast_k<0><<<dim3(32, 64, 8), 256, 0, stream>>>(W2, W2t, nullptr, 2048, 1024);

  // projections
  gemm_k<1, AM_Q, EP_QK><<<dim3(16, 16, 1), 256, 0, stream>>>(
      hallH, hallL, WqtH, WqtL, qH, qL, nullptr, 1024, 1024, 9, 0, nullptr, nullptr, nullptr);
  gemm_k<1, AM_ID, EP_QK><<<dim3(16, 32, 1), 256, 0, stream>>>(
      hallH, hallL, WktH, WktL, kH, kL, nullptr, 1024, 1024, 10, 0, nullptr, nullptr, nullptr);
  gemm_k<1, AM_ID, EP_VT><<<dim3(16, 32, 1), 256, 0, stream>>>(
      hallH, hallL, WvtH, WvtL, vtH, vtL, nullptr, 1024, 1024, 10, 0, nullptr, nullptr, nullptr);

  // attention
  attn_k<<<dim3(16, 32, 1), 256, 0, stream>>>(qH, qL, kH, kL, peH, peL, vtH, vtL, attH, attL);

  // output projection + LN1
  gemm_k<1, AM_ID, EP_F32><<<dim3(16, 16, 1), 256, 0, stream>>>(
      attH, attL, WotH, WotL, aproj, nullptr, nullptr, 1024, 1024, 0, 0, nullptr, nullptr, nullptr);
  ln1_k<<<2048, 256, 0, stream>>>(h, aproj, g1, b1n, h1, h1h);

  // gate + routing
  gate_k<<<512, 256, 0, stream>>>(h1, gW, gb, outIdx, scb, te, ctrl);
  scan_k<<<1, 64, 0, stream>>>(ctrl);
  scatter_k<<<8, 256, 0, stream>>>(te, ctrl, list, ppos);

  // expert FFNs
  gemm_k<0, AM_GA, EP_HE><<<dim3(16, 16, 8), 256, 0, stream>>>(
      h1h, nullptr, W1t, nullptr, he, nullptr, b1e, 1024, 1024, 0, 2048 * 1024, list, ctrl + 8, ctrl);
  gemm_k<0, AM_PA, EP_YE><<<dim3(8, 16, 8), 256, 0, stream>>>(
      he, nullptr, W2t, nullptr, ye, nullptr, b2e, 2048, 2048, 0, 1024 * 2048, nullptr, ctrl + 8, ctrl);

  // combine + LN2
  comb_ln2_k<<<2048, 256, 0, stream>>>(h1, ye, scb, ppos, g2, b2n, out);
}